// Round 5
// baseline (263.755 us; speedup 1.0000x reference)
//
#include <hip/hip_runtime.h>

typedef __bf16 bf16x8 __attribute__((ext_vector_type(8)));
typedef __bf16 bf16x4 __attribute__((ext_vector_type(4)));
typedef _Float16 half4 __attribute__((ext_vector_type(4)));
typedef _Float16 half8 __attribute__((ext_vector_type(8)));
typedef float f32x4 __attribute__((ext_vector_type(4)));

#define MFMA_BF16(a, b, c) __builtin_amdgcn_mfma_f32_16x16x32_bf16(a, b, c, 0, 0, 0)
#define MFMA_F16K32(a, b, c) __builtin_amdgcn_mfma_f32_16x16x32_f16(a, b, c, 0, 0, 0)
#define MFMA_F16K16(a, b, c) __builtin_amdgcn_mfma_f32_16x16x16f16(a, b, c, 0, 0, 0)
#define EXP2F(x) __builtin_amdgcn_exp2f(x)

constexpr int NSEQ = 2048, DIM = 1024, DH = 64;
constexpr int MROWS = 4096;
constexpr float QSCALE = 11.5415603271f;  // 8 * log2(e): logits in log2 units

__device__ __forceinline__ void split_bf16(float x, __bf16& h, __bf16& l) {
  h = (__bf16)x;
  l = (__bf16)(x - (float)h);
}

// async 16B/lane global->LDS; lds base wave-uniform, lane i lands at +i*16.
__device__ __forceinline__ void ld_lds16(void* lds, const void* g) {
  __builtin_amdgcn_global_load_lds(
      (const __attribute__((address_space(1))) void*)g,
      (__attribute__((address_space(3))) void*)lds, 16, 0, 0);
}

// ---------------------------------------------------------------------------
// Weight prep: transpose 64x64 f32 tiles.
// bx 0..15: w_q -> WTh/WTl rows 0..1023 (scaled by QSCALE)
// bx 16..47: w_vk -> WTh rows 1024..3071; WTl only for k (rows 1024..2047)
// bx 48..63: w_out -> WoT fp16 [n][k]
// ---------------------------------------------------------------------------
__global__ __launch_bounds__(256) void prep_w(
    const float* __restrict__ w_q, const float* __restrict__ w_vk,
    const float* __restrict__ w_out, __bf16* __restrict__ WTh,
    __bf16* __restrict__ WTl, _Float16* __restrict__ WoT) {
  __shared__ float T[64][65];
  const int t = threadIdx.x;
  const int bx = blockIdx.x, k0 = blockIdx.y * 64;
  const float* src;
  int srcN, n0, dstrow, mode;
  float scale;
  if (bx < 16) {
    src = w_q; srcN = 1024; n0 = bx * 64; dstrow = n0; scale = QSCALE; mode = 0;
  } else if (bx < 48) {
    src = w_vk; srcN = 2048; n0 = (bx - 16) * 64; dstrow = 1024 + n0;
    scale = 1.0f; mode = 0;
  } else {
    src = w_out; srcN = 1024; n0 = (bx - 48) * 64; dstrow = n0;
    scale = 1.0f; mode = 1;
  }
  {
    const int r = t >> 2, c4 = (t & 3) * 16;
    const float* s = src + (size_t)(k0 + r) * srcN + n0 + c4;
    float4 v0 = ((const float4*)s)[0], v1 = ((const float4*)s)[1],
           v2 = ((const float4*)s)[2], v3 = ((const float4*)s)[3];
    *(float4*)&T[r][c4 + 0] = v0;  *(float4*)&T[r][c4 + 4] = v1;
    *(float4*)&T[r][c4 + 8] = v2;  *(float4*)&T[r][c4 + 12] = v3;
  }
  __syncthreads();
  const int rn = t >> 2, kc = (t & 3) * 16;
  if (mode == 0) {
    bf16x8 hv[2], lv[2];
#pragma unroll
    for (int half = 0; half < 2; ++half)
#pragma unroll
      for (int j = 0; j < 8; ++j) {
        float x = T[kc + half * 8 + j][rn] * scale;
        __bf16 h, l;
        split_bf16(x, h, l);
        hv[half][j] = h; lv[half][j] = l;
      }
    __bf16* dh = WTh + (size_t)(dstrow + rn) * 1024 + k0 + kc;
    *(bf16x8*)dh = hv[0]; *(bf16x8*)(dh + 8) = hv[1];
    if (dstrow < 2048) {  // lo only for q, k (v uses hi-only weights)
      __bf16* dl = WTl + (size_t)(dstrow + rn) * 1024 + k0 + kc;
      *(bf16x8*)dl = lv[0]; *(bf16x8*)(dl + 8) = lv[1];
    }
  } else {
    half8 hv[2];
#pragma unroll
    for (int half = 0; half < 2; ++half)
#pragma unroll
      for (int j = 0; j < 8; ++j)
        hv[half][j] = (_Float16)T[kc + half * 8 + j][rn];
    _Float16* d = WoT + (size_t)(n0 + rn) * 1024 + k0 + kc;
    *(half8*)d = hv[0]; *(half8*)(d + 8) = hv[1];
  }
}

// ---------------------------------------------------------------------------
// x (f32) -> xh + xl (bf16 hi/lo). 8 elems/thread.
// ---------------------------------------------------------------------------
__global__ __launch_bounds__(256) void split_x(
    const float* __restrict__ x, __bf16* __restrict__ xh,
    __bf16* __restrict__ xl) {
  const size_t i = ((size_t)blockIdx.x * 256 + threadIdx.x) * 8;
  float4 a = *(const float4*)(x + i), b = *(const float4*)(x + i + 4);
  float v[8] = {a.x, a.y, a.z, a.w, b.x, b.y, b.z, b.w};
  bf16x8 h, l;
#pragma unroll
  for (int j = 0; j < 8; ++j) {
    __bf16 hh, ll;
    split_bf16(v[j], hh, ll);
    h[j] = hh; l[j] = ll;
  }
  *(bf16x8*)(xh + i) = h;
  *(bf16x8*)(xl + i) = l;
}

// ---------------------------------------------------------------------------
// Fused q/k/v projection, all-bf16 async staging (no in-loop split).
// kind = bn>>10: 0 -> qTh/qTl [1024][4096] (transposed, 8B vec stores);
// 1 -> KH/KL [4096][1024]; 2 -> VT fp16 [b][h][d][n].
// q/k: 3-product hi/lo; v: 2-product (xh+xl)*wh.
// ---------------------------------------------------------------------------
__global__ __launch_bounds__(256, 3) void proj4(
    const __bf16* __restrict__ xh, const __bf16* __restrict__ xl,
    const __bf16* __restrict__ WTh, const __bf16* __restrict__ WTl,
    __bf16* __restrict__ qTh, __bf16* __restrict__ qTl,
    __bf16* __restrict__ KH, __bf16* __restrict__ KL,
    _Float16* __restrict__ VT) {
  __shared__ __align__(16) __bf16 Xhs[128 * 32], Xls[128 * 32];
  __shared__ __align__(16) __bf16 Bhs[128 * 32], Bls[128 * 32];
  const int t = threadIdx.x;
  const int lane = t & 63, wave = t >> 6, quad = lane >> 4, lq = lane & 15;
  const int bn = blockIdx.x * 128, bm = blockIdx.y * 128;
  const int kind = bn >> 10;
  const int wm = (wave >> 1) * 64, wn = (wave & 1) * 64;

  // staging map: issue = 16 rows x 64B; chunk XOR-swizzled by row&3
  const int srow = lane >> 2;                  // 0..15
  const int schk = (lane & 3) ^ (srow & 3);    // 16B chunk 0..3
  const __bf16* xh_g = xh + (size_t)(bm + wave * 32 + srow) * DIM + schk * 8;
  const __bf16* xl_g = xl + (size_t)(bm + wave * 32 + srow) * DIM + schk * 8;
  const __bf16* bh_g = WTh + (size_t)(bn + wave * 32 + srow) * DIM + schk * 8;
  const __bf16* bl_g = WTl + (size_t)(bn + wave * 32 + srow) * DIM + schk * 8;
  const int sbase = (wave * 32) * 32;  // elem offset of this wave's rows

  // read-side: chunk quad at row r lives at chunk quad^(r&3); r&3 == lq&3
  const int swz = (quad ^ (lq & 3)) * 8;

  f32x4 acc[4][4];
#pragma unroll
  for (int i = 0; i < 4; ++i)
#pragma unroll
    for (int j = 0; j < 4; ++j) acc[i][j] = (f32x4){0.f, 0.f, 0.f, 0.f};

  for (int k0 = 0; k0 < DIM; k0 += 32) {
    ld_lds16(Xhs + sbase, xh_g + k0);
    ld_lds16(Xhs + sbase + 512, xh_g + k0 + 16 * DIM);
    ld_lds16(Xls + sbase, xl_g + k0);
    ld_lds16(Xls + sbase + 512, xl_g + k0 + 16 * DIM);
    ld_lds16(Bhs + sbase, bh_g + k0);
    ld_lds16(Bhs + sbase + 512, bh_g + k0 + 16 * DIM);
    if (kind < 2) {
      ld_lds16(Bls + sbase, bl_g + k0);
      ld_lds16(Bls + sbase + 512, bl_g + k0 + 16 * DIM);
    }
    __syncthreads();

    bf16x8 ah[4], al[4];
#pragma unroll
    for (int i = 0; i < 4; ++i) {
      const int off = (wm + i * 16 + lq) * 32 + swz;
      ah[i] = *(const bf16x8*)&Xhs[off];
      al[i] = *(const bf16x8*)&Xls[off];
    }
#pragma unroll
    for (int j = 0; j < 4; ++j) {
      const int boff = (wn + j * 16 + lq) * 32 + swz;
      bf16x8 bh = *(const bf16x8*)&Bhs[boff];
      if (kind < 2) {
        bf16x8 bl = *(const bf16x8*)&Bls[boff];
#pragma unroll
        for (int i = 0; i < 4; ++i) {
          acc[i][j] = MFMA_BF16(ah[i], bh, acc[i][j]);
          acc[i][j] = MFMA_BF16(al[i], bh, acc[i][j]);
          acc[i][j] = MFMA_BF16(ah[i], bl, acc[i][j]);
        }
      } else {
#pragma unroll
        for (int i = 0; i < 4; ++i) {
          acc[i][j] = MFMA_BF16(ah[i], bh, acc[i][j]);
          acc[i][j] = MFMA_BF16(al[i], bh, acc[i][j]);
        }
      }
    }
    __syncthreads();
  }

  if (kind == 0) {  // q -> transposed [dh_channel][token], 8B vector stores
#pragma unroll
    for (int i = 0; i < 4; ++i)
#pragma unroll
      for (int j = 0; j < 4; ++j) {
        const int col = bn + wn + j * 16 + lq;          // 0..1023
        const int token = bm + wm + i * 16 + quad * 4;  // multiple of 4
        bf16x4 h4, l4;
#pragma unroll
        for (int r = 0; r < 4; ++r) {
          __bf16 h, l;
          split_bf16(acc[i][j][r], h, l);
          h4[r] = h; l4[r] = l;
        }
        *(bf16x4*)(qTh + (size_t)col * MROWS + token) = h4;
        *(bf16x4*)(qTl + (size_t)col * MROWS + token) = l4;
      }
  } else if (kind == 1) {  // k token-major (attn needs A-frags by key row)
#pragma unroll
    for (int i = 0; i < 4; ++i)
#pragma unroll
      for (int j = 0; j < 4; ++j) {
        const int col = (bn - 1024) + wn + j * 16 + lq;
#pragma unroll
        for (int r = 0; r < 4; ++r) {
          const int row = bm + wm + i * 16 + quad * 4 + r;
          __bf16 h, l;
          split_bf16(acc[i][j][r], h, l);
          KH[(size_t)row * 1024 + col] = h;
          KL[(size_t)row * 1024 + col] = l;
        }
      }
  } else {  // v -> vT[b][h][d][n] fp16, 4 consecutive tokens / 8B store
#pragma unroll
    for (int i = 0; i < 4; ++i)
#pragma unroll
      for (int j = 0; j < 4; ++j) {
        const int c = (bn - 2048) + wn + j * 16 + lq;  // h*64 + d
        const int row0 = bm + wm + i * 16 + quad * 4;  // token
        const int b = row0 >> 11, n = row0 & 2047;
        const int h = c >> 6, d = c & 63;
        half4 o;
#pragma unroll
        for (int r = 0; r < 4; ++r) o[r] = (_Float16)acc[i][j][r];
        *(half4*)(VT + ((size_t)(b * 16 + h) * 64 + d) * 2048 + n) = o;
      }
  }
}

// ---------------------------------------------------------------------------
// Flash attention, TI=64 TJ=64: grid (32,32)=1024 blocks -> 4 blocks/CU,
// 4 waves x 16 q-rows. S^T = K.Q^T (bf16 3-product), softmax in regs (exp2),
// O^T = V^T.P^T (f16 K16, P^T straight from C-layout). LDS 24KB.
// ---------------------------------------------------------------------------
__global__ __launch_bounds__(256, 4) void attn4(
    const __bf16* __restrict__ qTh, const __bf16* __restrict__ qTl,
    const __bf16* __restrict__ kh, const __bf16* __restrict__ kl,
    const _Float16* __restrict__ vT, _Float16* __restrict__ ho) {
  __shared__ __align__(16) char smem[24576];
  __bf16* Khs = (__bf16*)smem;                // [64][64] chunk^=(row&7)
  __bf16* Kls = (__bf16*)(smem + 8192);
  _Float16* Vts = (_Float16*)(smem + 16384);  // [64 d][64 tok] chunk^=(row&7)
  _Float16* Ots = (_Float16*)smem;            // epilogue reuse [64][72]

  const int t = threadIdx.x;
  const int lane = t & 63, wave = t >> 6, quad = lane >> 4, lq = lane & 15;
  const int i0 = blockIdx.x * 64;
  const int bh = blockIdx.y, b = bh >> 4, head = bh & 15;
  const size_t rowbase = (size_t)b * NSEQ;
  const int qrow = i0 + wave * 16 + lq;

  // Q fragments (B-operand layout) from transposed q: coalesced b16 loads
  bf16x8 qfh[2], qfl[2];
#pragma unroll
  for (int hf = 0; hf < 2; ++hf)
#pragma unroll
    for (int jj = 0; jj < 8; ++jj) {
      const size_t c =
          (size_t)(head * 64 + hf * 32 + quad * 8 + jj) * MROWS + rowbase + qrow;
      qfh[hf][jj] = qTh[c];
      qfl[hf][jj] = qTl[c];
    }

  f32x4 o[4];
#pragma unroll
  for (int dt = 0; dt < 4; ++dt) o[dt] = (f32x4){0.f, 0.f, 0.f, 0.f};
  float mrun = -3.0e38f, lrun = 0.f;

  // staging: issue = 8 rows x 128B; chunk^=(row&7)
  const int srow = lane >> 3;             // 0..7
  const int schk = (lane & 7) ^ srow;     // 0..7
  const __bf16* khg =
      kh + (rowbase + wave * 16 + srow) * DIM + head * 64 + schk * 8;
  const __bf16* klg =
      kl + (rowbase + wave * 16 + srow) * DIM + head * 64 + schk * 8;
  const _Float16* vg =
      vT + ((size_t)bh * 64 + wave * 16 + srow) * NSEQ + schk * 8;
  const int sbase = (wave * 16) * 64;

  const int swzK0 = (quad ^ (lq & 7)) * 8;
  const int swzK1 = ((quad + 4) ^ (lq & 7)) * 8;

  for (int j0 = 0; j0 < NSEQ; j0 += 64) {
    ld_lds16(Khs + sbase, khg);
    ld_lds16(Khs + sbase + 8 * 64, khg + 8 * DIM);
    ld_lds16(Kls + sbase, klg);
    ld_lds16(Kls + sbase + 8 * 64, klg + 8 * DIM);
    ld_lds16(Vts + sbase, vg);
    ld_lds16(Vts + sbase + 8 * 64, vg + 8 * NSEQ);
    khg += (size_t)64 * DIM; klg += (size_t)64 * DIM; vg += 64;
    __syncthreads();

    // S^T = K.Q^T, hi/lo 3-product
    f32x4 s[4];
#pragma unroll
    for (int nt = 0; nt < 4; ++nt) {
      const int roff = (nt * 16 + lq) * 64;
      bf16x8 k0f = *(const bf16x8*)&Khs[roff + swzK0];
      bf16x8 k1f = *(const bf16x8*)&Khs[roff + swzK1];
      bf16x8 l0f = *(const bf16x8*)&Kls[roff + swzK0];
      bf16x8 l1f = *(const bf16x8*)&Kls[roff + swzK1];
      f32x4 sv = (f32x4){0.f, 0.f, 0.f, 0.f};
      sv = MFMA_BF16(k0f, qfh[0], sv);
      sv = MFMA_BF16(k1f, qfh[1], sv);
      sv = MFMA_BF16(k0f, qfl[0], sv);
      sv = MFMA_BF16(k1f, qfl[1], sv);
      sv = MFMA_BF16(l0f, qfh[0], sv);
      sv = MFMA_BF16(l1f, qfh[1], sv);
      s[nt] = sv;
    }

    // online softmax: qrow lane-resident; keys in 4 regs x 4 quads
    float mx = s[0][0];
#pragma unroll
    for (int nt = 0; nt < 4; ++nt)
#pragma unroll
      for (int r = 0; r < 4; ++r) mx = fmaxf(mx, s[nt][r]);
    mx = fmaxf(mx, __shfl_xor(mx, 16));
    mx = fmaxf(mx, __shfl_xor(mx, 32));
    const float mn = fmaxf(mrun, mx);
    const float alpha = EXP2F(mrun - mn);
    mrun = mn;
    float rs = 0.f;
    half4 pb[4];
#pragma unroll
    for (int nt = 0; nt < 4; ++nt)
#pragma unroll
      for (int r = 0; r < 4; ++r) {
        float p = EXP2F(s[nt][r] - mn);
        rs += p;
        pb[nt][r] = (_Float16)p;
      }
    rs += __shfl_xor(rs, 16);
    rs += __shfl_xor(rs, 32);
    lrun = lrun * alpha + rs;
#pragma unroll
    for (int dt = 0; dt < 4; ++dt) o[dt] *= alpha;

    // O^T += V^T.P^T
#pragma unroll
    for (int dt = 0; dt < 4; ++dt) {
      const int vrow = (dt * 16 + lq) * 64;
#pragma unroll
      for (int nt = 0; nt < 4; ++nt) {
        const int chk = (nt * 2 + (quad >> 1)) ^ (lq & 7);
        half4 va = *(const half4*)&Vts[vrow + chk * 8 + (quad & 1) * 4];
        o[dt] = MFMA_F16K16(va, pb[nt], o[dt]);
      }
    }
    __syncthreads();
  }

  // epilogue: O^T (qrow=lq, d=dt*16+quad*4+r) -> LDS -> coalesced f16 store
  const float inv = 1.0f / lrun;
  __syncthreads();
#pragma unroll
  for (int dt = 0; dt < 4; ++dt)
#pragma unroll
    for (int r = 0; r < 4; ++r)
      Ots[(wave * 16 + lq) * 72 + dt * 16 + quad * 4 + r] =
          (_Float16)(o[dt][r] * inv);
  __syncthreads();
  {
    const int row = t >> 2, qo = (t & 3) * 16;
    const _Float16* src = &Ots[row * 72 + qo];
    half8 o0 = ((const half8*)src)[0], o1 = ((const half8*)src)[1];
    _Float16* dst = ho + (rowbase + i0 + row) * DIM + head * 64 + qo;
    ((half8*)dst)[0] = o0;
    ((half8*)dst)[1] = o1;
  }
}

// ---------------------------------------------------------------------------
// out = ho(fp16) @ w_out (fp16 K32 MFMA, f32 out). 64x128 tiles.
// ---------------------------------------------------------------------------
__global__ __launch_bounds__(256, 2) void gemm_out(
    const _Float16* __restrict__ A, const _Float16* __restrict__ BT,
    float* __restrict__ C) {
  __shared__ __align__(16) _Float16 Ahs[64 * 32], Bhs[128 * 32];
  const int t = threadIdx.x;
  const int lane = t & 63, wave = t >> 6, quad = lane >> 4, lq = lane & 15;
  const int bn = blockIdx.x * 128, bm = blockIdx.y * 64;
  const int wm = (wave >> 1) * 32, wn = (wave & 1) * 64;

  const int bco = (lane & 7) ^ (lane >> 3);
  const int brow = 2 * (lane >> 3) + (bco >> 2);
  const int bcc = bco & 3;
  const _Float16* ag = A + (size_t)(bm + wave * 16 + brow) * DIM + bcc * 8;
  const _Float16* bg = BT + (size_t)(bn + wave * 32 + brow) * DIM + bcc * 8;
  const int swzB = ((((lq & 1) << 2) | quad) ^ ((lq >> 1) & 7)) * 8;

  f32x4 acc[2][4];
#pragma unroll
  for (int i = 0; i < 2; ++i)
#pragma unroll
    for (int j = 0; j < 4; ++j) acc[i][j] = (f32x4){0.f, 0.f, 0.f, 0.f};

  for (int k0 = 0; k0 < DIM; k0 += 32) {
    ld_lds16(Ahs + (wave * 16) * 32, ag);
#pragma unroll
    for (int q = 0; q < 2; ++q)
      ld_lds16(Bhs + (wave * 32 + q * 16) * 32, bg + (size_t)q * 16 * DIM);
    ag += 32; bg += 32;
    __syncthreads();
    half8 ah[2];
#pragma unroll
    for (int i = 0; i < 2; ++i) {
      const int row = wm + i * 16 + lq;
      ah[i] = *(const half8*)&Ahs[(row >> 1) * 64 + swzB];
    }
#pragma unroll
    for (int j = 0; j < 4; ++j) {
      const int row = wn + j * 16 + lq;
      half8 bh = *(const half8*)&Bhs[(row >> 1) * 64 + swzB];
#pragma unroll
      for (int i = 0; i < 2; ++i) acc[i][j] = MFMA_F16K32(ah[i], bh, acc[i][j]);
    }
    __syncthreads();
  }
#pragma unroll
  for (int i = 0; i < 2; ++i)
#pragma unroll
    for (int j = 0; j < 4; ++j) {
      const int col = bn + wn + j * 16 + lq;
#pragma unroll
      for (int r = 0; r < 4; ++r) {
        const int row = bm + wm + i * 16 + quad * 4 + r;
        C[(size_t)row * 1024 + col] = acc[i][j][r];
      }
    }
}

// ---------------------------------------------------------------------------
extern "C" void kernel_launch(void* const* d_in, const int* in_sizes, int n_in,
                              void* d_out, int out_size, void* d_ws,
                              size_t ws_size, hipStream_t stream) {
  const float* x     = (const float*)d_in[0];
  const float* w_q   = (const float*)d_in[1];
  const float* w_vk  = (const float*)d_in[2];
  const float* w_out = (const float*)d_in[3];
  float* out = (float*)d_out;

  char* w = (char*)d_ws;  // 60 MB used
  __bf16*   wTh = (__bf16*)(w);                   // [3072][1024] 6MB
  __bf16*   wTl = (__bf16*)(w + (6ull << 20));    // [2048][1024] 4MB (q,k lo)
  _Float16* woT = (_Float16*)(w + (10ull << 20)); // [1024][1024] 2MB
  __bf16*   qTh = (__bf16*)(w + (12ull << 20));   // [1024][4096] 8MB each
  __bf16*   qTl = (__bf16*)(w + (20ull << 20));
  __bf16*   khb = (__bf16*)(w + (28ull << 20));   // [4096][1024]
  __bf16*   klb = (__bf16*)(w + (36ull << 20));
  _Float16* vTb = (_Float16*)(w + (44ull << 20)); // [b][h][64][2048]
  _Float16* hob = (_Float16*)(w + (52ull << 20)); // [4096][1024]

  // x split lives in d_out (16MB) — dead before gemm_out writes it.
  __bf16* xh = (__bf16*)d_out;
  __bf16* xl = xh + (size_t)MROWS * DIM;

  dim3 blk(256);
  prep_w<<<dim3(64, 16), blk, 0, stream>>>(w_q, w_vk, w_out, wTh, wTl, woT);
  split_x<<<dim3(2048), blk, 0, stream>>>(x, xh, xl);
  proj4<<<dim3(24, 32), blk, 0, stream>>>(
      xh, xl, wTh, wTl, qTh, qTl, khb, klb, vTb);
  attn4<<<dim3(32, 32), blk, 0, stream>>>(qTh, qTl, khb, klb, vTb, hob);
  gemm_out<<<dim3(8, 64), blk, 0, stream>>>(hob, woT, out);
}